// Round 2
// baseline (435.504 us; speedup 1.0000x reference)
//
#include <hip/hip_runtime.h>
#include <math.h>

// Problem constants (from reference setup): B=4, S=512, D=512, F=256.
#define Bn 4
#define Sn 512
#define Dn 512
#define Fn 256
#define RROWS 8

struct Ent { float alpha; int ic; };  // ic = -1 => invalid (t >= L), write zeros

typedef float v4f __attribute__((ext_vector_type(4)));

// ---------------------------------------------------------------------------
// Fused kernel 1: blocks [0, PREP_BLKS) do the duration-scan + searchsorted
// table; blocks [PREP_BLKS, PREP_BLKS+MLP_BLKS) do the duration MLP.
// Both are tiny vs the expand kernel; fusing saves a launch and overlaps them.
// ---------------------------------------------------------------------------
#define PREP_BLKS (48128 / 256)   // T/256 = 188
#define MLP_BLKS  ((Bn * Sn) / RROWS)  // 256

__global__ __launch_bounds__(256) void prep_mlp_kernel(
        const int* __restrict__ dur, Ent* __restrict__ tab, int T,
        const float* __restrict__ x,  const float* __restrict__ W1,
        const float* __restrict__ b1, const float* __restrict__ W2,
        const float* __restrict__ b2, float* __restrict__ out_dur) {
    int tid = threadIdx.x;

    if (blockIdx.x < PREP_BLKS) {
        // ------- prep: scan durations[0] (512 ints, 256 threads, 2 each) -------
        __shared__ int cs[Sn];
        cs[tid]       = dur[tid];
        cs[tid + 256] = dur[tid + 256];
        __syncthreads();
        #pragma unroll
        for (int off = 1; off < Sn; off <<= 1) {
            int a0 = (tid >= off) ? cs[tid - off] : 0;
            int p1 = tid + 256;
            int a1 = (p1 >= off) ? cs[p1 - off] : 0;
            __syncthreads();
            cs[tid] += a0; cs[p1] += a1;
            __syncthreads();
        }
        int L = cs[Sn - 1];
        int t = blockIdx.x * 256 + tid;
        if (t >= T) return;
        Ent e;
        if (t >= L) {
            e.alpha = 0.f; e.ic = -1;
        } else {
            int lo = 0, hi = Sn;               // upper_bound (side='right')
            while (lo < hi) {
                int mid = (lo + hi) >> 1;
                if (cs[mid] <= t) lo = mid + 1; else hi = mid;
            }
            int ic = lo;
            int start = ic ? cs[ic - 1] : 0;
            int d = cs[ic] - start;
            e.ic = ic;
            e.alpha = (ic == Sn - 1) ? 0.f : (float)(t - start) / (float)d;
        }
        tab[t] = e;
    } else {
        // ------- MLP: softplus(relu(x@W1+b1)@W2+b2) for 8 rows per block -------
        __shared__ float xs[RROWS][Dn];        // 16 KB
        __shared__ float red[4][RROWS];
        int f = tid;                           // output feature 0..255
        int r0 = (blockIdx.x - PREP_BLKS) * RROWS;

        const float4* src = (const float4*)(x + (size_t)r0 * Dn);
        float4* dst = (float4*)(&xs[0][0]);
        for (int i = f; i < RROWS * Dn / 4; i += 256) dst[i] = src[i];
        __syncthreads();

        float acc[RROWS];
        #pragma unroll
        for (int r = 0; r < RROWS; r++) acc[r] = 0.f;

        for (int k = 0; k < Dn; k += 4) {
            float w0 = W1[(k + 0) * Fn + f];   // coalesced across f
            float w1 = W1[(k + 1) * Fn + f];
            float w2 = W1[(k + 2) * Fn + f];
            float w3 = W1[(k + 3) * Fn + f];
            #pragma unroll
            for (int r = 0; r < RROWS; r++) {
                float4 xv = *(const float4*)&xs[r][k];
                acc[r] += xv.x * w0 + xv.y * w1 + xv.z * w2 + xv.w * w3;
            }
        }

        float bb = b1[f], wf = W2[f];
        int lane = f & 63, wv = f >> 6;
        #pragma unroll
        for (int r = 0; r < RROWS; r++) {
            float h = acc[r] + bb;
            h = h > 0.f ? h : 0.f;
            float v = h * wf;
            #pragma unroll
            for (int off = 32; off > 0; off >>= 1) v += __shfl_down(v, off, 64);
            if (lane == 0) red[wv][r] = v;
        }
        __syncthreads();
        if (f < RROWS) {
            float z = red[0][f] + red[1][f] + red[2][f] + red[3][f] + b2[0];
            float sp = fmaxf(z, 0.f) + log1pf(expf(-fabsf(z)));  // stable softplus
            out_dur[r0 + f] = sp;
        }
    }
}

// ---------------------------------------------------------------------------
// Kernel 2: expanded[b, t, :] = (1-a)*x[b, ic, :] + a*x[b, ic+1, :]  (or zeros)
// One wave owns one full row (64 lanes x 2 float4 = 512 floats).
// grid (T/4, B) x 256 threads.
// ---------------------------------------------------------------------------
__global__ __launch_bounds__(256) void expand_kernel(const float* __restrict__ x,
                                                     const Ent* __restrict__ tab,
                                                     float* __restrict__ out, int T) {
    int lane = threadIdx.x & 63;
    int r = threadIdx.x >> 6;                 // 0..3 rows per block
    int t = blockIdx.x * 4 + r;
    int b = blockIdx.y;

    Ent e = tab[t];                           // wave-uniform 8B load (L1 broadcast)
    float* orow = out + ((size_t)b * T + t) * Dn;

    if (e.ic < 0) {
        v4f z = {0.f, 0.f, 0.f, 0.f};
        __builtin_nontemporal_store(z, (v4f*)orow + lane);
        __builtin_nontemporal_store(z, (v4f*)orow + lane + 64);
    } else {
        const float* xb = x + (size_t)b * (Sn * Dn);
        int icr = e.ic + 1; if (icr > Sn - 1) icr = Sn - 1;
        const float4* lp = (const float4*)(xb + (size_t)e.ic * Dn);
        const float4* rp = (const float4*)(xb + (size_t)icr * Dn);
        float a = e.alpha, na = 1.f - a;
        float4 l0 = lp[lane],      r0 = rp[lane];
        float4 l1 = lp[lane + 64], r1 = rp[lane + 64];
        v4f o0 = {na * l0.x + a * r0.x, na * l0.y + a * r0.y,
                  na * l0.z + a * r0.z, na * l0.w + a * r0.w};
        v4f o1 = {na * l1.x + a * r1.x, na * l1.y + a * r1.y,
                  na * l1.z + a * r1.z, na * l1.w + a * r1.w};
        __builtin_nontemporal_store(o0, (v4f*)orow + lane);
        __builtin_nontemporal_store(o1, (v4f*)orow + lane + 64);
    }
}

// ---------------------------------------------------------------------------
extern "C" void kernel_launch(void* const* d_in, const int* in_sizes, int n_in,
                              void* d_out, int out_size, void* d_ws, size_t ws_size,
                              hipStream_t stream) {
    const float* x   = (const float*)d_in[0];
    const float* W1  = (const float*)d_in[1];
    const float* b1  = (const float*)d_in[2];
    const float* W2  = (const float*)d_in[3];
    const float* b2  = (const float*)d_in[4];
    const int* durs  = (const int*)d_in[5];
    float* out = (float*)d_out;

    int T = (out_size - Bn * Sn) / (Bn * Dn);   // 48128
    Ent* tab = (Ent*)d_ws;                       // T * 8 bytes scratch

    float* dur_out = out + ((size_t)out_size - Bn * Sn);
    prep_mlp_kernel<<<dim3(PREP_BLKS + MLP_BLKS), 256, 0, stream>>>(
        durs, tab, T, x, W1, b1, W2, b2, dur_out);

    dim3 egrid(T / 4, Bn);
    expand_kernel<<<egrid, 256, 0, stream>>>(x, tab, out, T);
}